// Round 5
// baseline (388.161 us; speedup 1.0000x reference)
//
#include <hip/hip_runtime.h>

#define N_NODES  65536
#define D_FEAT   64
#define NBUCKETS 1024            // 64 rows per bucket
#define RPB      64              // rows per bucket
#define CHUNK    4096            // edges per partition/hist block
#define EPT      16              // edges per thread (256 thr * 16 = CHUNK)

// ---------- workspace layout ----------
// hist  : int[1024]        @ 0x0000
// base  : int[1025]        @ 0x1000
// gcur  : int[1024]        @ 0x3000
// pairs : u64[n_edges]     @ 0x10000   bucket-grouped {val:32 | row_local:6 | col:16}

// K1: bucket histogram (row>>6), per-block LDS then global merge.
__global__ void hist_kernel(const int* __restrict__ row, int* __restrict__ ghist, int n) {
    __shared__ int lh[NBUCKETS];
    int t = threadIdx.x;
    for (int j = t; j < NBUCKETS; j += 256) lh[j] = 0;
    __syncthreads();
    int cb = blockIdx.x * CHUNK;
    #pragma unroll
    for (int k = 0; k < EPT; ++k) {
        int i = cb + k * 256 + t;
        if (i < n) atomicAdd(&lh[row[i] >> 6], 1);
    }
    __syncthreads();
    for (int j = t; j < NBUCKETS; j += 256) {
        int c = lh[j];
        if (c) atomicAdd(&ghist[j], c);
    }
}

// K2: exclusive scan of 1024 bucket counts; init base[] and cursors.
__global__ void scan_kernel(const int* __restrict__ ghist, int* __restrict__ base,
                            int* __restrict__ gcur, int n_edges) {
    __shared__ int sh[NBUCKETS];
    int t = threadIdx.x;
    int c = ghist[t];
    sh[t] = c;
    __syncthreads();
    for (int d = 1; d < NBUCKETS; d <<= 1) {
        int add = (t >= d) ? sh[t - d] : 0;
        __syncthreads();
        sh[t] += add;
        __syncthreads();
    }
    int excl = sh[t] - c;
    base[t] = excl;
    gcur[t] = excl;
    if (t == NBUCKETS - 1) base[NBUCKETS] = n_edges;
}

// K3: partition edges into bucket-grouped order. One global atomic per
// (block,bucket) reserves a contiguous run -> clustered stores, low
// writeback amplification (vs per-edge random 4B scatter).
__global__ void partition_kernel(const int* __restrict__ row, const int* __restrict__ col,
                                 const float* __restrict__ val, int* __restrict__ gcur,
                                 unsigned long long* __restrict__ pairs, int n) {
    __shared__ int lcount[NBUCKETS];
    __shared__ int lbase[NBUCKETS];
    int t = threadIdx.x;
    for (int j = t; j < NBUCKETS; j += 256) lcount[j] = 0;
    __syncthreads();
    int cb = blockIdx.x * CHUNK;
    unsigned int saved[EPT];                 // {b:10 | row_local:6 | lrank:12}
    #pragma unroll
    for (int k = 0; k < EPT; ++k) {
        int i = cb + k * 256 + t;
        unsigned int s = 0xFFFFFFFFu;        // sentinel (real codes have top 4 bits 0)
        if (i < n) {
            int r = row[i];
            int b = r >> 6;
            int lrank = atomicAdd(&lcount[b], 1);     // < CHUNK = 4096, fits 12 bits
            s = ((unsigned)b << 18) | ((unsigned)(r & 63) << 12) | (unsigned)lrank;
        }
        saved[k] = s;
    }
    __syncthreads();
    for (int j = t; j < NBUCKETS; j += 256) {
        int c = lcount[j];
        if (c) lbase[j] = atomicAdd(&gcur[j], c);
    }
    __syncthreads();
    #pragma unroll
    for (int k = 0; k < EPT; ++k) {
        unsigned int s = saved[k];
        if (s == 0xFFFFFFFFu) continue;
        int i = cb + k * 256 + t;
        int b = s >> 18;
        unsigned rl = (s >> 12) & 63u;
        int lrank = s & 0xFFF;
        int pos = lbase[b] + lrank;
        unsigned long long pk = (unsigned long long)((unsigned)col[i] | (rl << 16))
                              | ((unsigned long long)__float_as_uint(val[i]) << 32);
        pairs[pos] = pk;
    }
}

// K4: bucket SpMM — one block per 64-row bucket, 64x64 f32 accumulator in LDS.
// wave = edge, lane = feature; LDS float atomics (ds_add_f32, conflict-free banks).
__global__ void spmm_bucket_kernel(const float* __restrict__ x, const int* __restrict__ base,
                                   const unsigned long long* __restrict__ pairs,
                                   float* __restrict__ out) {
    __shared__ float acc[RPB * D_FEAT];      // 16 KB
    int t = threadIdx.x;
    float4* a4 = (float4*)acc;
    #pragma unroll
    for (int j = 0; j < 4; ++j) a4[t + j * 256] = make_float4(0.f, 0.f, 0.f, 0.f);
    __syncthreads();

    int b = blockIdx.x;
    int beg = base[b], end = base[b + 1];
    int wid = t >> 6, lane = t & 63;
    int cnt = end - beg;
    int per = (cnt + 3) >> 2;                // contiguous slice per wave
    int s = beg + wid * per;
    int t_end = s + per < end ? s + per : end;
    int e = s;
    for (; e + 2 <= t_end; e += 2) {         // unroll 2: two gathers in flight
        unsigned long long p0 = pairs[e], p1 = pairs[e + 1];
        unsigned m0 = (unsigned)p0, m1 = (unsigned)p1;
        float v0 = __uint_as_float((unsigned)(p0 >> 32));
        float v1 = __uint_as_float((unsigned)(p1 >> 32));
        float xv0 = x[(size_t)(m0 & 0xFFFFu) * D_FEAT + lane];
        float xv1 = x[(size_t)(m1 & 0xFFFFu) * D_FEAT + lane];
        atomicAdd(&acc[((m0 >> 16) & 63u) * D_FEAT + lane], v0 * xv0);
        atomicAdd(&acc[((m1 >> 16) & 63u) * D_FEAT + lane], v1 * xv1);
    }
    if (e < t_end) {
        unsigned long long p = pairs[e];
        unsigned m = (unsigned)p;
        float v = __uint_as_float((unsigned)(p >> 32));
        atomicAdd(&acc[((m >> 16) & 63u) * D_FEAT + lane],
                  v * x[(size_t)(m & 0xFFFFu) * D_FEAT + lane]);
    }
    __syncthreads();

    const float4* af = (const float4*)acc;
    float4* o4 = (float4*)(out + (size_t)b * RPB * D_FEAT);
    #pragma unroll
    for (int j = 0; j < 4; ++j) o4[t + j * 256] = af[t + j * 256];   // coalesced flush
}

// Fallback (ws too small): atomic COO
__global__ void spmm_atomic_kernel(const float* __restrict__ x, const int* __restrict__ row,
                                   const int* __restrict__ col, const float* __restrict__ val,
                                   float* __restrict__ out, int n_edges) {
    int gid = blockIdx.x * blockDim.x + threadIdx.x;
    int e = gid >> 6;
    int lane = gid & 63;
    if (e >= n_edges) return;
    atomicAdd(&out[(size_t)row[e] * D_FEAT + lane], val[e] * x[(size_t)col[e] * D_FEAT + lane]);
}

extern "C" void kernel_launch(void* const* d_in, const int* in_sizes, int n_in,
                              void* d_out, int out_size, void* d_ws, size_t ws_size,
                              hipStream_t stream) {
    const float* x   = (const float*)d_in[0];
    const int*   row = (const int*)d_in[1];
    const int*   col = (const int*)d_in[2];
    const float* val = (const float*)d_in[3];
    float* out = (float*)d_out;
    int n_edges = in_sizes[1];

    size_t need = 0x10000 + (size_t)n_edges * sizeof(unsigned long long);
    if (ws_size < need) {
        hipMemsetAsync(d_out, 0, (size_t)out_size * sizeof(float), stream);
        int blocks = (n_edges * 64 + 255) / 256;
        spmm_atomic_kernel<<<blocks, 256, 0, stream>>>(x, row, col, val, out, n_edges);
        return;
    }

    char* ws = (char*)d_ws;
    int* hist = (int*)(ws);
    int* base = (int*)(ws + 0x1000);
    int* gcur = (int*)(ws + 0x3000);
    unsigned long long* pairs = (unsigned long long*)(ws + 0x10000);

    hipMemsetAsync(hist, 0, NBUCKETS * sizeof(int), stream);

    int nchunks = (n_edges + CHUNK - 1) / CHUNK;
    hist_kernel<<<nchunks, 256, 0, stream>>>(row, hist, n_edges);
    scan_kernel<<<1, NBUCKETS, 0, stream>>>(hist, base, gcur, n_edges);
    partition_kernel<<<nchunks, 256, 0, stream>>>(row, col, val, gcur, pairs, n_edges);
    spmm_bucket_kernel<<<NBUCKETS, 256, 0, stream>>>(x, base, pairs, out);
}